// Round 1
// baseline (1540.223 us; speedup 1.0000x reference)
//
#include <hip/hip_runtime.h>
#include <math.h>

#define BB 32
#define NN 1024
#define MM 1024
#define FF 64
#define INF_ 1e30f

// ---------------- norms: one wave per row (x and y concatenated) --------------
__global__ __launch_bounds__(256) void norms_kernel(const float* __restrict__ x,
                                                    const float* __restrict__ y,
                                                    float* __restrict__ xn,
                                                    float* __restrict__ yn) {
    int gw = (blockIdx.x * 256 + threadIdx.x) >> 6;   // global wave = row index
    int lane = threadIdx.x & 63;
    int total = BB * NN + BB * MM;
    if (gw >= total) return;
    const float* src; float* dst; int row;
    if (gw < BB * NN) { src = x; dst = xn; row = gw; }
    else             { src = y; dst = yn; row = gw - BB * NN; }
    float v = src[(size_t)row * FF + lane];
    float s = v * v;
    #pragma unroll
    for (int d = 32; d > 0; d >>= 1) s += __shfl_xor(s, d, 64);
    if (lane == 0) dst[row] = s;
}

// ---------------- cost: 64x64 tile per 256-thread block, 4x4 per thread -------
__global__ __launch_bounds__(256) void cost_kernel(const float* __restrict__ x,
                                                   const float* __restrict__ y,
                                                   const float* __restrict__ xn,
                                                   const float* __restrict__ yn,
                                                   float* __restrict__ cost) {
    __shared__ float Xs[FF][68];   // [k][row], padded
    __shared__ float Ys[FF][68];
    const int b    = blockIdx.z;
    const int row0 = blockIdx.y * 64;
    const int col0 = blockIdx.x * 64;
    const int tid  = threadIdx.x;
    const float* xb = x + (size_t)b * NN * FF;
    const float* yb = y + (size_t)b * MM * FF;

    #pragma unroll
    for (int cc = 0; cc < 4; ++cc) {
        int s  = tid + cc * 256;      // 0..1023 float4 slots
        int r  = s >> 4;              // tile row 0..63
        int kq = s & 15;              // k-quad 0..15
        float4 vx = *(const float4*)(xb + (size_t)(row0 + r) * FF + kq * 4);
        float4 vy = *(const float4*)(yb + (size_t)(col0 + r) * FF + kq * 4);
        Xs[kq*4+0][r] = vx.x; Xs[kq*4+1][r] = vx.y; Xs[kq*4+2][r] = vx.z; Xs[kq*4+3][r] = vx.w;
        Ys[kq*4+0][r] = vy.x; Ys[kq*4+1][r] = vy.y; Ys[kq*4+2][r] = vy.z; Ys[kq*4+3][r] = vy.w;
    }
    __syncthreads();

    const int tx = tid & 15, ty = tid >> 4;
    float acc[4][4] = {};
    #pragma unroll 16
    for (int k = 0; k < FF; ++k) {
        float4 a  = *(const float4*)&Xs[k][ty * 4];
        float4 bb = *(const float4*)&Ys[k][tx * 4];
        float av[4] = {a.x, a.y, a.z, a.w};
        float bv[4] = {bb.x, bb.y, bb.z, bb.w};
        #pragma unroll
        for (int r = 0; r < 4; ++r)
            #pragma unroll
            for (int c = 0; c < 4; ++c)
                acc[r][c] += av[r] * bv[c];
    }

    #pragma unroll
    for (int r = 0; r < 4; ++r) {
        int row = row0 + ty * 4 + r;
        float xnv = xn[b * NN + row];
        float4 o;
        float* op = (float*)&o;
        #pragma unroll
        for (int c = 0; c < 4; ++c) {
            int col = col0 + tx * 4 + c;
            float v = xnv + yn[b * MM + col] - 2.0f * acc[r][c];
            op[c] = sqrtf(fmaxf(v, 0.0f));
        }
        *(float4*)(cost + ((size_t)b * NN + row) * MM + col0 + tx * 4) = o;
    }
}

// ---------------- DTW DP: one block (1024 threads) per batch ------------------
__global__ __launch_bounds__(1024) void dtw_kernel(const float* __restrict__ cost,
                                                   float* __restrict__ out) {
    const int b    = blockIdx.x;
    const int tid  = threadIdx.x;
    const int lane = tid & 63;
    const int wid  = tid >> 6;    // 0..15
    __shared__ float P[MM];
    __shared__ float part_sum[16];
    __shared__ float part_min[16];

    P[tid] = INF_;
    __syncthreads();

    const float* cb = cost + (size_t)b * NN * MM;
    float result = 0.0f;

    for (int i = 0; i < NN; ++i) {
        float c    = cb[(size_t)i * MM + tid];
        float up   = P[tid];
        float diag = (tid == 0) ? (i == 0 ? 0.0f : INF_) : P[tid - 1];
        float m    = fminf(up, diag);

        // inclusive prefix sum of c across the block
        float s = c;
        #pragma unroll
        for (int d = 1; d < 64; d <<= 1) {
            float t = __shfl_up(s, d, 64);
            if (lane >= d) s += t;
        }
        if (lane == 63) part_sum[wid] = s;
        __syncthreads();
        if (tid < 16) {
            float p = part_sum[tid];
            #pragma unroll
            for (int d = 1; d < 16; d <<= 1) {
                float t = __shfl_up(p, d, 64);
                if (tid >= d) p += t;
            }
            part_sum[tid] = p;   // inclusive scan of wave totals
        }
        __syncthreads();
        float C = s + (wid > 0 ? part_sum[wid - 1] : 0.0f);

        float z = c + m - C;
        // inclusive prefix min of z across the block
        float w = z;
        #pragma unroll
        for (int d = 1; d < 64; d <<= 1) {
            float t = __shfl_up(w, d, 64);
            if (lane >= d) w = fminf(w, t);
        }
        if (lane == 63) part_min[wid] = w;
        __syncthreads();
        if (tid < 16) {
            float p = part_min[tid];
            #pragma unroll
            for (int d = 1; d < 16; d <<= 1) {
                float t = __shfl_up(p, d, 64);
                if (tid >= d) p = fminf(p, t);
            }
            part_min[tid] = p;
        }
        __syncthreads();
        float wm  = (wid > 0) ? fminf(w, part_min[wid - 1]) : w;
        float cur = C + wm;

        P[tid] = cur;
        __syncthreads();
        if (i == NN - 1 && tid == MM - 1) result = cur;
    }
    if (tid == MM - 1) out[b] = result;
}

// ---------------- fused fallback (no workspace): cost on the fly --------------
__global__ __launch_bounds__(1024) void dtw_fused_kernel(const float* __restrict__ x,
                                                         const float* __restrict__ y,
                                                         float* __restrict__ out) {
    const int b    = blockIdx.x;
    const int tid  = threadIdx.x;
    const int lane = tid & 63;
    const int wid  = tid >> 6;
    __shared__ float P[MM];
    __shared__ float xrow[FF];
    __shared__ float part_sum[16];
    __shared__ float part_min[16];

    // y row for this thread in registers
    float yr[FF];
    const float* yrow = y + ((size_t)b * MM + tid) * FF;
    #pragma unroll
    for (int q = 0; q < FF / 4; ++q) {
        float4 v = ((const float4*)yrow)[q];
        yr[q*4+0] = v.x; yr[q*4+1] = v.y; yr[q*4+2] = v.z; yr[q*4+3] = v.w;
    }

    P[tid] = INF_;
    __syncthreads();

    const float* xb = x + (size_t)b * NN * FF;
    float result = 0.0f;

    for (int i = 0; i < NN; ++i) {
        if (tid < FF) xrow[tid] = xb[(size_t)i * FF + tid];
        float up   = P[tid];
        float diag = (tid == 0) ? (i == 0 ? 0.0f : INF_) : P[tid - 1];
        float m    = fminf(up, diag);
        __syncthreads();

        float ss = 0.0f;
        #pragma unroll 16
        for (int k = 0; k < FF; ++k) {
            float d = xrow[k] - yr[k];
            ss += d * d;
        }
        float c = sqrtf(ss);

        float s = c;
        #pragma unroll
        for (int d = 1; d < 64; d <<= 1) {
            float t = __shfl_up(s, d, 64);
            if (lane >= d) s += t;
        }
        if (lane == 63) part_sum[wid] = s;
        __syncthreads();
        if (tid < 16) {
            float p = part_sum[tid];
            #pragma unroll
            for (int d = 1; d < 16; d <<= 1) {
                float t = __shfl_up(p, d, 64);
                if (tid >= d) p += t;
            }
            part_sum[tid] = p;
        }
        __syncthreads();
        float C = s + (wid > 0 ? part_sum[wid - 1] : 0.0f);

        float z = c + m - C;
        float w = z;
        #pragma unroll
        for (int d = 1; d < 64; d <<= 1) {
            float t = __shfl_up(w, d, 64);
            if (lane >= d) w = fminf(w, t);
        }
        if (lane == 63) part_min[wid] = w;
        __syncthreads();
        if (tid < 16) {
            float p = part_min[tid];
            #pragma unroll
            for (int d = 1; d < 16; d <<= 1) {
                float t = __shfl_up(p, d, 64);
                if (tid >= d) p = fminf(p, t);
            }
            part_min[tid] = p;
        }
        __syncthreads();
        float wm  = (wid > 0) ? fminf(w, part_min[wid - 1]) : w;
        float cur = C + wm;

        P[tid] = cur;
        __syncthreads();
        if (i == NN - 1 && tid == MM - 1) result = cur;
    }
    if (tid == MM - 1) out[b] = result;
}

extern "C" void kernel_launch(void* const* d_in, const int* in_sizes, int n_in,
                              void* d_out, int out_size, void* d_ws, size_t ws_size,
                              hipStream_t stream) {
    const float* x = (const float*)d_in[0];
    const float* y = (const float*)d_in[1];
    float* out = (float*)d_out;

    size_t need = (size_t)BB * NN * MM * sizeof(float)
                + (size_t)BB * NN * sizeof(float)
                + (size_t)BB * MM * sizeof(float);

    if (ws_size >= need) {
        float* cost = (float*)d_ws;
        float* xn = cost + (size_t)BB * NN * MM;
        float* yn = xn + (size_t)BB * NN;

        int total_rows = BB * NN + BB * MM;            // one wave per row
        int blocks = (total_rows + 3) / 4;             // 4 waves per 256-thread block
        hipLaunchKernelGGL(norms_kernel, dim3(blocks), dim3(256), 0, stream,
                           x, y, xn, yn);
        hipLaunchKernelGGL(cost_kernel, dim3(MM / 64, NN / 64, BB), dim3(256), 0, stream,
                           x, y, xn, yn, cost);
        hipLaunchKernelGGL(dtw_kernel, dim3(BB), dim3(1024), 0, stream, cost, out);
    } else {
        hipLaunchKernelGGL(dtw_fused_kernel, dim3(BB), dim3(1024), 0, stream, x, y, out);
    }
}

// Round 2
// 550.904 us; speedup vs baseline: 2.7958x; 2.7958x over previous
//
#include <hip/hip_runtime.h>
#include <math.h>

#define BB 32
#define NN 1024
#define MM 1024
#define FF 64
#define INF_ 1e30f

// ---------------- norms: one wave per row (x and y concatenated) --------------
__global__ __launch_bounds__(256) void norms_kernel(const float* __restrict__ x,
                                                    const float* __restrict__ y,
                                                    float* __restrict__ xn,
                                                    float* __restrict__ yn) {
    int gw = (blockIdx.x * 256 + threadIdx.x) >> 6;   // global wave = row index
    int lane = threadIdx.x & 63;
    int total = BB * NN + BB * MM;
    if (gw >= total) return;
    const float* src; float* dst; int row;
    if (gw < BB * NN) { src = x; dst = xn; row = gw; }
    else             { src = y; dst = yn; row = gw - BB * NN; }
    float v = src[(size_t)row * FF + lane];
    float s = v * v;
    #pragma unroll
    for (int d = 32; d > 0; d >>= 1) s += __shfl_xor(s, d, 64);
    if (lane == 0) dst[row] = s;
}

// ---------------- cost: 64x64 tile per 256-thread block, 4x4 per thread -------
__global__ __launch_bounds__(256) void cost_kernel(const float* __restrict__ x,
                                                   const float* __restrict__ y,
                                                   const float* __restrict__ xn,
                                                   const float* __restrict__ yn,
                                                   float* __restrict__ cost) {
    __shared__ float Xs[FF][68];   // [k][row], padded
    __shared__ float Ys[FF][68];
    const int b    = blockIdx.z;
    const int row0 = blockIdx.y * 64;
    const int col0 = blockIdx.x * 64;
    const int tid  = threadIdx.x;
    const float* xb = x + (size_t)b * NN * FF;
    const float* yb = y + (size_t)b * MM * FF;

    #pragma unroll
    for (int cc = 0; cc < 4; ++cc) {
        int s  = tid + cc * 256;      // 0..1023 float4 slots
        int r  = s >> 4;              // tile row 0..63
        int kq = s & 15;              // k-quad 0..15
        float4 vx = *(const float4*)(xb + (size_t)(row0 + r) * FF + kq * 4);
        float4 vy = *(const float4*)(yb + (size_t)(col0 + r) * FF + kq * 4);
        Xs[kq*4+0][r] = vx.x; Xs[kq*4+1][r] = vx.y; Xs[kq*4+2][r] = vx.z; Xs[kq*4+3][r] = vx.w;
        Ys[kq*4+0][r] = vy.x; Ys[kq*4+1][r] = vy.y; Ys[kq*4+2][r] = vy.z; Ys[kq*4+3][r] = vy.w;
    }
    __syncthreads();

    const int tx = tid & 15, ty = tid >> 4;
    float acc[4][4] = {};
    #pragma unroll 16
    for (int k = 0; k < FF; ++k) {
        float4 a  = *(const float4*)&Xs[k][ty * 4];
        float4 bb = *(const float4*)&Ys[k][tx * 4];
        float av[4] = {a.x, a.y, a.z, a.w};
        float bv[4] = {bb.x, bb.y, bb.z, bb.w};
        #pragma unroll
        for (int r = 0; r < 4; ++r)
            #pragma unroll
            for (int c = 0; c < 4; ++c)
                acc[r][c] += av[r] * bv[c];
    }

    #pragma unroll
    for (int r = 0; r < 4; ++r) {
        int row = row0 + ty * 4 + r;
        float xnv = xn[b * NN + row];
        float4 o;
        float* op = (float*)&o;
        #pragma unroll
        for (int c = 0; c < 4; ++c) {
            int col = col0 + tx * 4 + c;
            float v = xnv + yn[b * MM + col] - 2.0f * acc[r][c];
            op[c] = sqrtf(fmaxf(v, 0.0f));
        }
        *(float4*)(cost + ((size_t)b * NN + row) * MM + col0 + tx * 4) = o;
    }
}

// ---------------- DPP wave64 inclusive scans (gfx9 idiom) ----------------------
__device__ __forceinline__ float wave_iscan_add(float v) {
    int t;
    t = __builtin_amdgcn_update_dpp(0, __float_as_int(v), 0x111, 0xf, 0xf, false); v += __int_as_float(t);
    t = __builtin_amdgcn_update_dpp(0, __float_as_int(v), 0x112, 0xf, 0xf, false); v += __int_as_float(t);
    t = __builtin_amdgcn_update_dpp(0, __float_as_int(v), 0x114, 0xf, 0xf, false); v += __int_as_float(t);
    t = __builtin_amdgcn_update_dpp(0, __float_as_int(v), 0x118, 0xf, 0xf, false); v += __int_as_float(t);
    t = __builtin_amdgcn_update_dpp(0, __float_as_int(v), 0x142, 0xa, 0xf, false); v += __int_as_float(t);
    t = __builtin_amdgcn_update_dpp(0, __float_as_int(v), 0x143, 0xc, 0xf, false); v += __int_as_float(t);
    return v;
}

__device__ __forceinline__ float wave_iscan_min(float v) {
    const int ID = __float_as_int(INF_);
    int t;
    t = __builtin_amdgcn_update_dpp(ID, __float_as_int(v), 0x111, 0xf, 0xf, false); v = fminf(v, __int_as_float(t));
    t = __builtin_amdgcn_update_dpp(ID, __float_as_int(v), 0x112, 0xf, 0xf, false); v = fminf(v, __int_as_float(t));
    t = __builtin_amdgcn_update_dpp(ID, __float_as_int(v), 0x114, 0xf, 0xf, false); v = fminf(v, __int_as_float(t));
    t = __builtin_amdgcn_update_dpp(ID, __float_as_int(v), 0x118, 0xf, 0xf, false); v = fminf(v, __int_as_float(t));
    t = __builtin_amdgcn_update_dpp(ID, __float_as_int(v), 0x142, 0xa, 0xf, false); v = fminf(v, __int_as_float(t));
    t = __builtin_amdgcn_update_dpp(ID, __float_as_int(v), 0x143, 0xc, 0xf, false); v = fminf(v, __int_as_float(t));
    return v;
}

// ---------------- one DP row: 16 cols/lane, zero barriers ----------------------
__device__ __forceinline__ void dtw_row(int i, int lane,
                                        float4 v0, float4 v1, float4 v2, float4 v3,
                                        float P[16]) {
    float c[16] = {v0.x, v0.y, v0.z, v0.w,
                   v1.x, v1.y, v1.z, v1.w,
                   v2.x, v2.y, v2.z, v2.w,
                   v3.x, v3.y, v3.z, v3.w};
    // in-lane inclusive cumsum
    float s[16];
    s[0] = c[0];
    #pragma unroll
    for (int j = 1; j < 16; ++j) s[j] = s[j - 1] + c[j];
    float T = s[15];
    float I = wave_iscan_add(T);
    float Osum = I - T;                       // exclusive add-scan of lane totals

    // m[j] = min(up, diag); diag crosses lane boundary at col 0
    float dIn = __shfl_up(P[15], 1, 64);
    if (lane == 0) dIn = (i == 0) ? 0.0f : INF_;
    float m0 = fminf(P[0], dIn);

    // r[j] = cummin_j (m[j] - s[j-1]),   s[-1] = 0
    float r[16];
    r[0] = m0;
    #pragma unroll
    for (int j = 1; j < 16; ++j)
        r[j] = fminf(r[j - 1], fminf(P[j], P[j - 1]) - s[j - 1]);

    // cross-lane exclusive min of adjusted lane totals
    float t2 = r[15] - Osum;
    float ts = __shfl_up(t2, 1, 64);
    if (lane == 0) ts = INF_;
    float Omin = wave_iscan_min(ts);
    float Q = Osum + Omin;                    // lane-uniform

    #pragma unroll
    for (int j = 0; j < 16; ++j) P[j] = s[j] + fminf(r[j], Q);
}

// ---------------- DTW DP: one wave per batch ----------------------------------
__global__ __launch_bounds__(64) void dtw_wave_kernel(const float* __restrict__ cost,
                                                      float* __restrict__ out) {
    const int b    = blockIdx.x;
    const int lane = threadIdx.x;
    const float* cb = cost + (size_t)b * NN * MM + (size_t)lane * 16;

    float4 A0, A1, A2, A3, B0, B1, B2, B3;
    A0 = ((const float4*)cb)[0]; A1 = ((const float4*)cb)[1];
    A2 = ((const float4*)cb)[2]; A3 = ((const float4*)cb)[3];

    float P[16];
    #pragma unroll
    for (int j = 0; j < 16; ++j) P[j] = INF_;

    for (int i = 0; i < NN; i += 2) {
        const float* r1 = cb + (size_t)(i + 1) * MM;
        B0 = ((const float4*)r1)[0]; B1 = ((const float4*)r1)[1];
        B2 = ((const float4*)r1)[2]; B3 = ((const float4*)r1)[3];

        dtw_row(i, lane, A0, A1, A2, A3, P);

        int i2 = (i + 2 < NN) ? (i + 2) : (NN - 1);   // clamp: harmless dup load
        const float* r2 = cb + (size_t)i2 * MM;
        A0 = ((const float4*)r2)[0]; A1 = ((const float4*)r2)[1];
        A2 = ((const float4*)r2)[2]; A3 = ((const float4*)r2)[3];

        dtw_row(i + 1, lane, B0, B1, B2, B3, P);
    }
    if (lane == 63) out[b] = P[15];
}

// ---------------- fused fallback (no workspace): cost on the fly --------------
__global__ __launch_bounds__(1024) void dtw_fused_kernel(const float* __restrict__ x,
                                                         const float* __restrict__ y,
                                                         float* __restrict__ out) {
    const int b    = blockIdx.x;
    const int tid  = threadIdx.x;
    const int lane = tid & 63;
    const int wid  = tid >> 6;
    __shared__ float P[MM];
    __shared__ float xrow[FF];
    __shared__ float part_sum[16];
    __shared__ float part_min[16];

    float yr[FF];
    const float* yrow = y + ((size_t)b * MM + tid) * FF;
    #pragma unroll
    for (int q = 0; q < FF / 4; ++q) {
        float4 v = ((const float4*)yrow)[q];
        yr[q*4+0] = v.x; yr[q*4+1] = v.y; yr[q*4+2] = v.z; yr[q*4+3] = v.w;
    }

    P[tid] = INF_;
    __syncthreads();

    const float* xb = x + (size_t)b * NN * FF;
    float result = 0.0f;

    for (int i = 0; i < NN; ++i) {
        if (tid < FF) xrow[tid] = xb[(size_t)i * FF + tid];
        float up   = P[tid];
        float diag = (tid == 0) ? (i == 0 ? 0.0f : INF_) : P[tid - 1];
        float m    = fminf(up, diag);
        __syncthreads();

        float ss = 0.0f;
        #pragma unroll 16
        for (int k = 0; k < FF; ++k) {
            float d = xrow[k] - yr[k];
            ss += d * d;
        }
        float c = sqrtf(ss);

        float s = c;
        #pragma unroll
        for (int d = 1; d < 64; d <<= 1) {
            float t = __shfl_up(s, d, 64);
            if (lane >= d) s += t;
        }
        if (lane == 63) part_sum[wid] = s;
        __syncthreads();
        if (tid < 16) {
            float p = part_sum[tid];
            #pragma unroll
            for (int d = 1; d < 16; d <<= 1) {
                float t = __shfl_up(p, d, 64);
                if (tid >= d) p += t;
            }
            part_sum[tid] = p;
        }
        __syncthreads();
        float C = s + (wid > 0 ? part_sum[wid - 1] : 0.0f);

        float z = c + m - C;
        float w = z;
        #pragma unroll
        for (int d = 1; d < 64; d <<= 1) {
            float t = __shfl_up(w, d, 64);
            if (lane >= d) w = fminf(w, t);
        }
        if (lane == 63) part_min[wid] = w;
        __syncthreads();
        if (tid < 16) {
            float p = part_min[tid];
            #pragma unroll
            for (int d = 1; d < 16; d <<= 1) {
                float t = __shfl_up(p, d, 64);
                if (tid >= d) p = fminf(p, t);
            }
            part_min[tid] = p;
        }
        __syncthreads();
        float wm  = (wid > 0) ? fminf(w, part_min[wid - 1]) : w;
        float cur = C + wm;

        P[tid] = cur;
        __syncthreads();
        if (i == NN - 1 && tid == MM - 1) result = cur;
    }
    if (tid == MM - 1) out[b] = result;
}

extern "C" void kernel_launch(void* const* d_in, const int* in_sizes, int n_in,
                              void* d_out, int out_size, void* d_ws, size_t ws_size,
                              hipStream_t stream) {
    const float* x = (const float*)d_in[0];
    const float* y = (const float*)d_in[1];
    float* out = (float*)d_out;

    size_t need = (size_t)BB * NN * MM * sizeof(float)
                + (size_t)BB * NN * sizeof(float)
                + (size_t)BB * MM * sizeof(float);

    if (ws_size >= need) {
        float* cost = (float*)d_ws;
        float* xn = cost + (size_t)BB * NN * MM;
        float* yn = xn + (size_t)BB * NN;

        int total_rows = BB * NN + BB * MM;
        int blocks = (total_rows + 3) / 4;
        hipLaunchKernelGGL(norms_kernel, dim3(blocks), dim3(256), 0, stream,
                           x, y, xn, yn);
        hipLaunchKernelGGL(cost_kernel, dim3(MM / 64, NN / 64, BB), dim3(256), 0, stream,
                           x, y, xn, yn, cost);
        hipLaunchKernelGGL(dtw_wave_kernel, dim3(BB), dim3(64), 0, stream, cost, out);
    } else {
        hipLaunchKernelGGL(dtw_fused_kernel, dim3(BB), dim3(1024), 0, stream, x, y, out);
    }
}

// Round 3
// 509.816 us; speedup vs baseline: 3.0211x; 1.0806x over previous
//
#include <hip/hip_runtime.h>
#include <math.h>

#define BB 32
#define NN 1024
#define MM 1024
#define FF 64
#define INF_ 1e30f

// ---------------- norms: one wave per row (x and y concatenated) --------------
__global__ __launch_bounds__(256) void norms_kernel(const float* __restrict__ x,
                                                    const float* __restrict__ y,
                                                    float* __restrict__ xn,
                                                    float* __restrict__ yn) {
    int gw = (blockIdx.x * 256 + threadIdx.x) >> 6;   // global wave = row index
    int lane = threadIdx.x & 63;
    int total = BB * NN + BB * MM;
    if (gw >= total) return;
    const float* src; float* dst; int row;
    if (gw < BB * NN) { src = x; dst = xn; row = gw; }
    else             { src = y; dst = yn; row = gw - BB * NN; }
    float v = src[(size_t)row * FF + lane];
    float s = v * v;
    #pragma unroll
    for (int d = 32; d > 0; d >>= 1) s += __shfl_xor(s, d, 64);
    if (lane == 0) dst[row] = s;
}

// ---------------- cost: 64x64 tile per 256-thread block, 4x4 per thread -------
__global__ __launch_bounds__(256) void cost_kernel(const float* __restrict__ x,
                                                   const float* __restrict__ y,
                                                   const float* __restrict__ xn,
                                                   const float* __restrict__ yn,
                                                   float* __restrict__ cost) {
    __shared__ float Xs[FF][68];   // [k][row], padded
    __shared__ float Ys[FF][68];
    const int b    = blockIdx.z;
    const int row0 = blockIdx.y * 64;
    const int col0 = blockIdx.x * 64;
    const int tid  = threadIdx.x;
    const float* xb = x + (size_t)b * NN * FF;
    const float* yb = y + (size_t)b * MM * FF;

    #pragma unroll
    for (int cc = 0; cc < 4; ++cc) {
        int s  = tid + cc * 256;      // 0..1023 float4 slots
        int r  = s >> 4;              // tile row 0..63
        int kq = s & 15;              // k-quad 0..15
        float4 vx = *(const float4*)(xb + (size_t)(row0 + r) * FF + kq * 4);
        float4 vy = *(const float4*)(yb + (size_t)(col0 + r) * FF + kq * 4);
        Xs[kq*4+0][r] = vx.x; Xs[kq*4+1][r] = vx.y; Xs[kq*4+2][r] = vx.z; Xs[kq*4+3][r] = vx.w;
        Ys[kq*4+0][r] = vy.x; Ys[kq*4+1][r] = vy.y; Ys[kq*4+2][r] = vy.z; Ys[kq*4+3][r] = vy.w;
    }
    __syncthreads();

    const int tx = tid & 15, ty = tid >> 4;
    float acc[4][4] = {};
    #pragma unroll 16
    for (int k = 0; k < FF; ++k) {
        float4 a  = *(const float4*)&Xs[k][ty * 4];
        float4 bb = *(const float4*)&Ys[k][tx * 4];
        float av[4] = {a.x, a.y, a.z, a.w};
        float bv[4] = {bb.x, bb.y, bb.z, bb.w};
        #pragma unroll
        for (int r = 0; r < 4; ++r)
            #pragma unroll
            for (int c = 0; c < 4; ++c)
                acc[r][c] += av[r] * bv[c];
    }

    #pragma unroll
    for (int r = 0; r < 4; ++r) {
        int row = row0 + ty * 4 + r;
        float xnv = xn[b * NN + row];
        float4 o;
        float* op = (float*)&o;
        #pragma unroll
        for (int c = 0; c < 4; ++c) {
            int col = col0 + tx * 4 + c;
            float v = xnv + yn[b * MM + col] - 2.0f * acc[r][c];
            op[c] = sqrtf(fmaxf(v, 0.0f));
        }
        *(float4*)(cost + ((size_t)b * NN + row) * MM + col0 + tx * 4) = o;
    }
}

// ---------------- DPP helpers (gfx9 encodings, live on gfx950) ----------------
__device__ __forceinline__ float dpp_wave_shr1(float v, float oldv) {
    // lane i <- lane i-1; lane 0 <- oldv  (bound_ctrl=false keeps old)
    int t = __builtin_amdgcn_update_dpp(__float_as_int(oldv), __float_as_int(v),
                                        0x138, 0xf, 0xf, false);
    return __int_as_float(t);
}

__device__ __forceinline__ float wave_iscan_add(float v) {
    int t;
    t = __builtin_amdgcn_update_dpp(0, __float_as_int(v), 0x111, 0xf, 0xf, false); v += __int_as_float(t);
    t = __builtin_amdgcn_update_dpp(0, __float_as_int(v), 0x112, 0xf, 0xf, false); v += __int_as_float(t);
    t = __builtin_amdgcn_update_dpp(0, __float_as_int(v), 0x114, 0xf, 0xf, false); v += __int_as_float(t);
    t = __builtin_amdgcn_update_dpp(0, __float_as_int(v), 0x118, 0xf, 0xf, false); v += __int_as_float(t);
    t = __builtin_amdgcn_update_dpp(0, __float_as_int(v), 0x142, 0xa, 0xf, false); v += __int_as_float(t);
    t = __builtin_amdgcn_update_dpp(0, __float_as_int(v), 0x143, 0xc, 0xf, false); v += __int_as_float(t);
    return v;
}

__device__ __forceinline__ float wave_iscan_min(float v) {
    const int ID = __float_as_int(INF_);
    int t;
    t = __builtin_amdgcn_update_dpp(ID, __float_as_int(v), 0x111, 0xf, 0xf, false); v = fminf(v, __int_as_float(t));
    t = __builtin_amdgcn_update_dpp(ID, __float_as_int(v), 0x112, 0xf, 0xf, false); v = fminf(v, __int_as_float(t));
    t = __builtin_amdgcn_update_dpp(ID, __float_as_int(v), 0x114, 0xf, 0xf, false); v = fminf(v, __int_as_float(t));
    t = __builtin_amdgcn_update_dpp(ID, __float_as_int(v), 0x118, 0xf, 0xf, false); v = fminf(v, __int_as_float(t));
    t = __builtin_amdgcn_update_dpp(ID, __float_as_int(v), 0x142, 0xa, 0xf, false); v = fminf(v, __int_as_float(t));
    t = __builtin_amdgcn_update_dpp(ID, __float_as_int(v), 0x143, 0xc, 0xf, false); v = fminf(v, __int_as_float(t));
    return v;
}

// ---------------- row buffer (statically indexed registers) -------------------
struct RowBuf { float4 q0, q1, q2, q3; };

__device__ __forceinline__ void load_row(RowBuf& R, const float* p) {
    R.q0 = ((const float4*)p)[0];
    R.q1 = ((const float4*)p)[1];
    R.q2 = ((const float4*)p)[2];
    R.q3 = ((const float4*)p)[3];
}

// ---------------- one DP row: 16 cols/lane, zero barriers, zero LDS ----------
__device__ __forceinline__ void dtw_row(float bnd, const RowBuf& R, float P[16]) {
    float c[16] = {R.q0.x, R.q0.y, R.q0.z, R.q0.w,
                   R.q1.x, R.q1.y, R.q1.z, R.q1.w,
                   R.q2.x, R.q2.y, R.q2.z, R.q2.w,
                   R.q3.x, R.q3.y, R.q3.z, R.q3.w};
    // in-lane inclusive cumsum
    float s[16];
    s[0] = c[0];
    #pragma unroll
    for (int j = 1; j < 16; ++j) s[j] = s[j - 1] + c[j];
    float T = s[15];
    float I = wave_iscan_add(T);
    float Osum = I - T;                       // exclusive add-scan of lane totals

    // diag across lane boundary (lane 0 <- bnd)
    float dIn = dpp_wave_shr1(P[15], bnd);

    // r[j] = cummin_j ( min(up,diag)[j] - s[j-1] ),  s[-1] = 0
    float r[16];
    r[0] = fminf(P[0], dIn);
    #pragma unroll
    for (int j = 1; j < 16; ++j)
        r[j] = fminf(r[j - 1], fminf(P[j], P[j - 1]) - s[j - 1]);

    // cross-lane exclusive min of adjusted lane totals
    float ts   = dpp_wave_shr1(r[15] - Osum, INF_);
    float Omin = wave_iscan_min(ts);
    float Q    = Osum + Omin;                 // lane-uniform

    #pragma unroll
    for (int j = 0; j < 16; ++j) P[j] = s[j] + fminf(r[j], Q);
}

// ---------------- DTW DP: one wave per batch, 4-deep prefetch ring ------------
__global__ __launch_bounds__(64) void dtw_wave_kernel(const float* __restrict__ cost,
                                                      float* __restrict__ out) {
    const int b    = blockIdx.x;
    const int lane = threadIdx.x;
    const float* cb = cost + (size_t)b * NN * MM + (size_t)lane * 16;

    RowBuf R0, R1, R2, R3;
    load_row(R0, cb + 0 * (size_t)MM);
    load_row(R1, cb + 1 * (size_t)MM);
    load_row(R2, cb + 2 * (size_t)MM);
    load_row(R3, cb + 3 * (size_t)MM);

    float P[16];
    #pragma unroll
    for (int j = 0; j < 16; ++j) P[j] = INF_;

    for (int i = 0; i < NN; i += 4) {
        float bnd0 = (i == 0) ? 0.0f : INF_;

        dtw_row(bnd0, R0, P);
        if (i + 4 < NN) load_row(R0, cb + (size_t)(i + 4) * MM);

        dtw_row(INF_, R1, P);
        if (i + 5 < NN) load_row(R1, cb + (size_t)(i + 5) * MM);

        dtw_row(INF_, R2, P);
        if (i + 6 < NN) load_row(R2, cb + (size_t)(i + 6) * MM);

        dtw_row(INF_, R3, P);
        if (i + 7 < NN) load_row(R3, cb + (size_t)(i + 7) * MM);
    }
    if (lane == 63) out[b] = P[15];
}

// ---------------- fused fallback (no workspace): cost on the fly --------------
__global__ __launch_bounds__(1024) void dtw_fused_kernel(const float* __restrict__ x,
                                                         const float* __restrict__ y,
                                                         float* __restrict__ out) {
    const int b    = blockIdx.x;
    const int tid  = threadIdx.x;
    const int lane = tid & 63;
    const int wid  = tid >> 6;
    __shared__ float P[MM];
    __shared__ float xrow[FF];
    __shared__ float part_sum[16];
    __shared__ float part_min[16];

    float yr[FF];
    const float* yrow = y + ((size_t)b * MM + tid) * FF;
    #pragma unroll
    for (int q = 0; q < FF / 4; ++q) {
        float4 v = ((const float4*)yrow)[q];
        yr[q*4+0] = v.x; yr[q*4+1] = v.y; yr[q*4+2] = v.z; yr[q*4+3] = v.w;
    }

    P[tid] = INF_;
    __syncthreads();

    const float* xb = x + (size_t)b * NN * FF;
    float result = 0.0f;

    for (int i = 0; i < NN; ++i) {
        if (tid < FF) xrow[tid] = xb[(size_t)i * FF + tid];
        float up   = P[tid];
        float diag = (tid == 0) ? (i == 0 ? 0.0f : INF_) : P[tid - 1];
        float m    = fminf(up, diag);
        __syncthreads();

        float ss = 0.0f;
        #pragma unroll 16
        for (int k = 0; k < FF; ++k) {
            float d = xrow[k] - yr[k];
            ss += d * d;
        }
        float c = sqrtf(ss);

        float s = c;
        #pragma unroll
        for (int d = 1; d < 64; d <<= 1) {
            float t = __shfl_up(s, d, 64);
            if (lane >= d) s += t;
        }
        if (lane == 63) part_sum[wid] = s;
        __syncthreads();
        if (tid < 16) {
            float p = part_sum[tid];
            #pragma unroll
            for (int d = 1; d < 16; d <<= 1) {
                float t = __shfl_up(p, d, 64);
                if (tid >= d) p += t;
            }
            part_sum[tid] = p;
        }
        __syncthreads();
        float C = s + (wid > 0 ? part_sum[wid - 1] : 0.0f);

        float z = c + m - C;
        float w = z;
        #pragma unroll
        for (int d = 1; d < 64; d <<= 1) {
            float t = __shfl_up(w, d, 64);
            if (lane >= d) w = fminf(w, t);
        }
        if (lane == 63) part_min[wid] = w;
        __syncthreads();
        if (tid < 16) {
            float p = part_min[tid];
            #pragma unroll
            for (int d = 1; d < 16; d <<= 1) {
                float t = __shfl_up(p, d, 64);
                if (tid >= d) p = fminf(p, t);
            }
            part_min[tid] = p;
        }
        __syncthreads();
        float wm  = (wid > 0) ? fminf(w, part_min[wid - 1]) : w;
        float cur = C + wm;

        P[tid] = cur;
        __syncthreads();
        if (i == NN - 1 && tid == MM - 1) result = cur;
    }
    if (tid == MM - 1) out[b] = result;
}

extern "C" void kernel_launch(void* const* d_in, const int* in_sizes, int n_in,
                              void* d_out, int out_size, void* d_ws, size_t ws_size,
                              hipStream_t stream) {
    const float* x = (const float*)d_in[0];
    const float* y = (const float*)d_in[1];
    float* out = (float*)d_out;

    size_t need = (size_t)BB * NN * MM * sizeof(float)
                + (size_t)BB * NN * sizeof(float)
                + (size_t)BB * MM * sizeof(float);

    if (ws_size >= need) {
        float* cost = (float*)d_ws;
        float* xn = cost + (size_t)BB * NN * MM;
        float* yn = xn + (size_t)BB * NN;

        int total_rows = BB * NN + BB * MM;
        int blocks = (total_rows + 3) / 4;
        hipLaunchKernelGGL(norms_kernel, dim3(blocks), dim3(256), 0, stream,
                           x, y, xn, yn);
        hipLaunchKernelGGL(cost_kernel, dim3(MM / 64, NN / 64, BB), dim3(256), 0, stream,
                           x, y, xn, yn, cost);
        hipLaunchKernelGGL(dtw_wave_kernel, dim3(BB), dim3(64), 0, stream, cost, out);
    } else {
        hipLaunchKernelGGL(dtw_fused_kernel, dim3(BB), dim3(1024), 0, stream, x, y, out);
    }
}